// Round 13
// baseline (307.680 us; speedup 1.0000x reference)
//
#include <hip/hip_runtime.h>

typedef unsigned int uint;
typedef unsigned short ushort;
typedef unsigned char uchar;

#define EPS 1e-5f
#define BSH 8        // bucket = 256 dst nodes
#define NBMAX 512
#define BCAP 10240   // LDS-cached bucket capacity (edges) in bucket_final
#define SCAT_E 8192  // edges per scatter/hist block

typedef __attribute__((ext_vector_type(8))) short short8;
typedef __attribute__((ext_vector_type(16))) float f32x16;
typedef __attribute__((ext_vector_type(2))) float float2v;
typedef __attribute__((ext_vector_type(2))) _Float16 half2v;
typedef __attribute__((ext_vector_type(8))) _Float16 f16x8;

static __device__ __forceinline__ ushort f2h(float f) {
    return __builtin_bit_cast(ushort, (_Float16)f);
}
static __device__ __forceinline__ half2v u2h(uint u) {
    return __builtin_bit_cast(half2v, u);
}

// ---------------------------------------------------------------- CSR build (atomic-free allocation)
// S1: per-block LDS histogram -> cnt2d[blk][NB] (coalesced row write, no atomics)
__global__ __launch_bounds__(256) void hist2d_kernel(const int* __restrict__ dst,
                                                     int* __restrict__ cnt2d, int E, int NB) {
    __shared__ int lh[NBMAX];
    const int tid = threadIdx.x;
    for (int t = tid; t < NB; t += 256) lh[t] = 0;
    __syncthreads();
    const int base = blockIdx.x * SCAT_E, end = min(base + SCAT_E, E);
    for (int i = base + tid; i < end; i += 256) atomicAdd(&lh[dst[i] >> BSH], 1);
    __syncthreads();
    int* row = cnt2d + (size_t)blockIdx.x * NB;
    for (int t = tid; t < NB; t += 256) row[t] = lh[t];
}

// S2: per-bucket exclusive scan of cnt2d over the block dimension (one wave per bucket)
__global__ __launch_bounds__(256) void scan2d_kernel(int* __restrict__ cnt2d,
                                                     int* __restrict__ bcnt, int NB, int NBLK) {
    const int b = blockIdx.x * 4 + (threadIdx.x >> 6);
    if (b >= NB) return;
    const int lane = threadIdx.x & 63;
    int carry = 0;
    for (int c0 = 0; c0 < NBLK; c0 += 64) {
        int idx = c0 + lane;
        int v = (idx < NBLK) ? cnt2d[(size_t)idx * NB + b] : 0;
        int inc = v;
#pragma unroll
        for (int d = 1; d < 64; d <<= 1) { int u = __shfl_up(inc, d); if (lane >= d) inc += u; }
        if (idx < NBLK) cnt2d[(size_t)idx * NB + b] = inc - v + carry;
        carry += __shfl(inc, 63);
    }
    if (lane == 0) bcnt[b] = carry;
}

// S3: exclusive scan bcnt -> gcur (single block); also writes gcur[nb] = total
__global__ void scan_gcur_kernel(const int* __restrict__ bcnt, int* __restrict__ gcur, int nb) {
    __shared__ int wsum[4];
    const int t = threadIdx.x;
    int e[4], s = 0;
#pragma unroll
    for (int k = 0; k < 4; ++k) {
        int idx = t * 4 + k;
        e[k] = (idx < nb) ? bcnt[idx] : 0;
        s += e[k];
    }
    int lane = t & 63, w = t >> 6;
    int v = s;
#pragma unroll
    for (int d = 1; d < 64; d <<= 1) { int u = __shfl_up(v, d); if (lane >= d) v += u; }
    if (lane == 63) wsum[w] = v;
    __syncthreads();
    int off = 0;
    for (int k = 0; k < w; ++k) off += wsum[k];
    int run = off + v - s;
#pragma unroll
    for (int k = 0; k < 4; ++k) {
        int idx = t * 4 + k;
        if (idx < nb) gcur[idx] = run;
        run += e[k];
    }
    if (t == 0) gcur[nb] = wsum[0] + wsum[1] + wsum[2] + wsum[3];
}

// S4: LDS counting sort per block, run-contiguous stage writes; run base is
// gcur[b] + cnt2d[blk][b] -- fully deterministic, zero global atomics.
// packed 4B: src | (dst & 255) << 17
__global__ __launch_bounds__(256) void bucket_scatter_kernel(const int* __restrict__ src,
                                                             const int* __restrict__ dst,
                                                             const int* __restrict__ gcur,
                                                             const int* __restrict__ cnt2d,
                                                             uint* __restrict__ stage,
                                                             int E, int NB) {
    __shared__ uint sedge[SCAT_E];
    __shared__ ushort sbkt[SCAT_E];
    __shared__ int lh[NBMAX];
    __shared__ int lofs[NBMAX + 1];
    __shared__ int lbase[NBMAX];
    __shared__ int wsum[4];
    const int tid = threadIdx.x;
    const int base = blockIdx.x * SCAT_E;
    const int len = min(base + SCAT_E, E) - base;
    const int* myrow = cnt2d + (size_t)blockIdx.x * NB;

    for (int t = tid; t < NB; t += 256) lh[t] = 0;
    __syncthreads();
    // pass 1: histogram
    for (int i = tid; i < len; i += 256) atomicAdd(&lh[dst[base + i] >> BSH], 1);
    __syncthreads();
    // local exclusive scan (2 elems/thread, NB<=512) + deterministic global bases
    const int i0 = tid * 2, i1 = tid * 2 + 1;
    int e0 = (i0 < NB) ? lh[i0] : 0;
    int e1 = (i1 < NB) ? lh[i1] : 0;
    int s = e0 + e1;
    int lane = tid & 63, w = tid >> 6;
    int v = s;
#pragma unroll
    for (int d = 1; d < 64; d <<= 1) { int u = __shfl_up(v, d); if (lane >= d) v += u; }
    if (lane == 63) wsum[w] = v;
    __syncthreads();
    int off = 0;
    for (int k = 0; k < w; ++k) off += wsum[k];
    int run = off + v - s;
    if (i0 <= NB) lofs[i0] = run;
    if (i0 < NB) lbase[i0] = gcur[i0] + myrow[i0];
    run += e0;
    if (i1 <= NB) lofs[i1] = run;
    if (i1 < NB) lbase[i1] = gcur[i1] + myrow[i1];
    __syncthreads();
    // reset cursors
    for (int t = tid; t < NB; t += 256) lh[t] = 0;
    __syncthreads();
    // pass 2: LDS scatter into sorted order, recording bucket per position
    for (int i = tid; i < len; i += 256) {
        int d = dst[base + i];
        int b = d >> BSH;
        int r = atomicAdd(&lh[b], 1);
        int pos = lofs[b] + r;
        sedge[pos] = (uint)src[base + i] | ((uint)(d & 255) << 17);
        sbkt[pos] = (ushort)b;
    }
    __syncthreads();
    // pass 3: linear copy; consecutive i -> consecutive stage slots within runs
    for (int i = tid; i < len; i += 256) {
        int b = sbkt[i];
        stage[lbase[b] + (i - lofs[b])] = sedge[i];
    }
}

// B: per-bucket finalize: LDS hist -> scan -> rowptr + place via LDS cursors
__global__ __launch_bounds__(256) void bucket_final_kernel(const uint* __restrict__ stage,
                                                           const int* __restrict__ gcur,
                                                           int* __restrict__ rowptr,
                                                           int* __restrict__ eidx, int n) {
    __shared__ uint sbuf[BCAP];
    __shared__ int cnt[256];
    __shared__ int wsum[4];
    const int b = blockIdx.x, tid = threadIdx.x;
    const int r0 = gcur[b];
    const int r1 = gcur[b + 1];
    const int len = r1 - r0;
    const bool inl = (len <= BCAP);
    cnt[tid] = 0;
    if (inl) for (int i = tid; i < len; i += 256) sbuf[i] = stage[r0 + i];
    __syncthreads();
    for (int i = tid; i < len; i += 256) {
        uint v = inl ? sbuf[i] : stage[r0 + i];
        atomicAdd(&cnt[v >> 17], 1);
    }
    __syncthreads();
    int orig = cnt[tid], v = orig;
    int lane = tid & 63, w = tid >> 6;
#pragma unroll
    for (int d2 = 1; d2 < 64; d2 <<= 1) { int u = __shfl_up(v, d2); if (lane >= d2) v += u; }
    if (lane == 63) wsum[w] = v;
    __syncthreads();
    int off = 0;
    for (int k = 0; k < w; ++k) off += wsum[k];
    const int excl = r0 + off + v - orig;   // absolute exclusive slot base
    const int d = (b << BSH) + tid;
    if (d <= n) rowptr[d] = excl;           // last bucket covers rowptr[n] = E
    __syncthreads();
    cnt[tid] = excl;
    __syncthreads();
    for (int i = tid; i < len; i += 256) {
        uint pv = inl ? sbuf[i] : stage[r0 + i];
        int slot = atomicAdd(&cnt[pv >> 17], 1);
        eidx[slot] = (int)(pv & 0x1FFFFu);
    }
}

// ---------------------------------------------------------------- layer 1 fused (Cin = 1)
// 16-lane group per node; writes f16 h1 row AND fp8 shadow row
__global__ __launch_bounds__(256) void layer1_fused_kernel(
    const float* __restrict__ x, const int* __restrict__ rowptr, const int* __restrict__ eidx,
    const float* __restrict__ Wrel, const float* __restrict__ brel,
    const float* __restrict__ Wroot, const float* __restrict__ gamma,
    const float* __restrict__ beta, const float* __restrict__ mean,
    const float* __restrict__ var, ushort* __restrict__ h1, uchar* __restrict__ h8, int n) {
    __shared__ float A[128], B[128], C[128];
    const int tid = threadIdx.x;
    if (tid < 128) {
        float sc = gamma[tid] * rsqrtf(var[tid] + EPS);
        A[tid] = Wrel[tid] * sc;
        B[tid] = Wroot[tid] * sc;
        C[tid] = beta[tid] + (brel[tid] - mean[tid]) * sc;
    }
    __syncthreads();
    const int g16 = tid >> 4;
    const int l16 = tid & 15;
    const int node = blockIdx.x * 16 + g16;
    if (node >= n) return;
    const int e0 = rowptr[node], e1 = rowptr[node + 1];
    float acc = 0.f;
    for (int e = e0 + l16; e < e1; e += 16) acc += x[eidx[e]];
#pragma unroll
    for (int d = 1; d < 16; d <<= 1) acc += __shfl_xor(acc, d);
    const float xi = x[node];
    float vv[8];
    uint4 o;
    ushort* op = (ushort*)&o;
#pragma unroll
    for (int j = 0; j < 8; ++j) {
        int c = l16 * 8 + j;
        vv[j] = fmaxf(acc * A[c] + xi * B[c] + C[c], 0.f);
        op[j] = f2h(vv[j]);
    }
    *((uint4*)(h1 + (size_t)node * 128) + l16) = o;
    uint p0 = 0, p1 = 0;
    p0 = __builtin_amdgcn_cvt_pk_fp8_f32(vv[0], vv[1], 0, 0);
    p0 = __builtin_amdgcn_cvt_pk_fp8_f32(vv[2], vv[3], p0, 1);
    p1 = __builtin_amdgcn_cvt_pk_fp8_f32(vv[4], vv[5], 0, 0);
    p1 = __builtin_amdgcn_cvt_pk_fp8_f32(vv[6], vv[7], p1, 1);
    uint2 o8; o8.x = p0; o8.y = p1;
    ((uint2*)(h8 + (size_t)node * 128))[l16] = o8;
}

// ---------------------------------------------------------------- aggregation (fp8 source, H=128)
// one node per wave; 8 lanes per edge (uint4 = 16B of the 128B fp8 row); 8 edge slots
// per wave-load (1KB/instr); srcs broadcast via shfl; f32 accum via v_cvt_pk_f32_fp8.
__global__ __launch_bounds__(256) void gather_fp8_kernel(const uchar* __restrict__ h8,
                                                         const int* __restrict__ rowptr,
                                                         const int* __restrict__ eidx,
                                                         ushort* __restrict__ agg, int n) {
    const int node = blockIdx.x * 4 + (threadIdx.x >> 6);
    if (node >= n) return;
    const int lane = threadIdx.x & 63;
    const int g = lane >> 3;        // edge slot 0..7
    const int c16 = lane & 7;       // 16B slice of the 128B row
    const uint4* hq = (const uint4*)h8;   // 8 uint4 per row
    const int e0 = rowptr[node];
    const int len = rowptr[node + 1] - e0;

    float2v a[8];
#pragma unroll
    for (int i = 0; i < 8; ++i) a[i] = {0.f, 0.f};

#define ACC16(u)                                                       \
    do {                                                               \
        a[0] += __builtin_amdgcn_cvt_pk_f32_fp8((int)(u).x, 0);        \
        a[1] += __builtin_amdgcn_cvt_pk_f32_fp8((int)(u).x, 1);        \
        a[2] += __builtin_amdgcn_cvt_pk_f32_fp8((int)(u).y, 0);        \
        a[3] += __builtin_amdgcn_cvt_pk_f32_fp8((int)(u).y, 1);        \
        a[4] += __builtin_amdgcn_cvt_pk_f32_fp8((int)(u).z, 0);        \
        a[5] += __builtin_amdgcn_cvt_pk_f32_fp8((int)(u).z, 1);        \
        a[6] += __builtin_amdgcn_cvt_pk_f32_fp8((int)(u).w, 0);        \
        a[7] += __builtin_amdgcn_cvt_pk_f32_fp8((int)(u).w, 1);        \
    } while (0)

    for (int base = 0; base < len; base += 64) {
        const int cnt = min(len - base, 64);
        int msrc = (lane < cnt) ? eidx[e0 + base + lane] : 0;
        const int kfull = cnt >> 3;     // complete groups of 8 edges
        int k = 0;
        for (; k + 4 <= kfull; k += 4) {    // 32 edges, 4 uint4 (64B) in flight per lane
            uint4 u[4];
#pragma unroll
            for (int s = 0; s < 4; ++s) {
                int src = __shfl(msrc, (k + s) * 8 + g);
                u[s] = hq[(size_t)src * 8 + c16];
            }
#pragma unroll
            for (int s = 0; s < 4; ++s) ACC16(u[s]);
        }
        for (; k < kfull; ++k) {
            int src = __shfl(msrc, k * 8 + g);
            uint4 u = hq[(size_t)src * 8 + c16];
            ACC16(u);
        }
        const int rem = cnt & 7;
        if (rem) {
            int idx = (kfull << 3) + g;     // kfull<=7 here -> idx <= 63
            int src = __shfl(msrc, idx);
            if (g < rem) {
                uint4 u = hq[(size_t)src * 8 + c16];
                ACC16(u);
            }
        }
    }
#undef ACC16

    // reduce across the 8 edge slots (lanes with equal c16)
#pragma unroll
    for (int d = 8; d <= 32; d <<= 1) {
#pragma unroll
        for (int i = 0; i < 8; ++i) {
            a[i][0] += __shfl_xor(a[i][0], d);
            a[i][1] += __shfl_xor(a[i][1], d);
        }
    }
    if (g == 0) {
        uint4 o0, o1;
        ushort* p0 = (ushort*)&o0;
        ushort* p1 = (ushort*)&o1;
#pragma unroll
        for (int i = 0; i < 4; ++i) {
            p0[i * 2]     = f2h(a[i][0]);
            p0[i * 2 + 1] = f2h(a[i][1]);
            p1[i * 2]     = f2h(a[i + 4][0]);
            p1[i * 2 + 1] = f2h(a[i + 4][1]);
        }
        ((uint4*)agg)[(size_t)node * 16 + c16 * 2]     = o0;
        ((uint4*)agg)[(size_t)node * 16 + c16 * 2 + 1] = o1;
    }
}

// ---------------------------------------------------------------- weight fragment prep
// WF layout: [half][kt 0..7][ct 0..3][lane 0..63][j 0..7]  (f16)
// frag element = W_half[ct*32 + (lane&31)][kt*16 + (lane>>5)*8 + j]
__global__ void wf_prep_kernel(const float* __restrict__ W0, const float* __restrict__ W1,
                               const float* __restrict__ W2, const float* __restrict__ W3,
                               ushort* __restrict__ WF2, ushort* __restrict__ WF3) {
    int i = blockIdx.x * 256 + threadIdx.x;   // 65536 threads
    const float* Ws[4] = {W0, W1, W2, W3};
    int mat = i >> 14;
    int m = i & 16383;
    int j = m & 7, lane = (m >> 3) & 63, ct = (m >> 9) & 3, kt = (m >> 11) & 7;
    int row = ct * 32 + (lane & 31);
    int col = kt * 16 + ((lane >> 5) * 8) + j;
    float v = Ws[mat][row * 128 + col];
    ushort* dstp = (mat < 2) ? WF2 : WF3;
    dstp[(mat & 1) * 16384 + m] = f2h(v);
}

// ---------------------------------------------------------------- fused conv via MFMA (f16)
// POOL=0: write f16 (+fp8 shadow if WRITE8). POOL=1: no h-output; fold BN+Wout,
// per-node dot -> LDS -> per-graph accumulation (mean-pool numerator + counts).
template <int RELU, int WRITE8, int POOL>
__global__ __launch_bounds__(256) void conv_mfma_kernel(
    const short* __restrict__ agg, const short* __restrict__ hin,
    const short* __restrict__ WF,
    const float* __restrict__ brel, const float* __restrict__ gamma,
    const float* __restrict__ beta, const float* __restrict__ mean,
    const float* __restrict__ var,
    ushort* __restrict__ hout, uchar* __restrict__ h8out,
    const int* __restrict__ batch, const float* __restrict__ Wout,
    float* __restrict__ gscal, int* __restrict__ gcnt, int n) {
    __shared__ float pnode[128];
    __shared__ float pg[64];
    __shared__ int pc[64];
    const int tid = threadIdx.x;
    if (POOL && tid < 64) { pg[tid] = 0.f; pc[tid] = 0; }
    const int lane = tid & 63;
    const int wt = blockIdx.x * 4 + (tid >> 6);
    const int node0 = wt * 32;
    if (!POOL && node0 >= n) return;
    const int r32 = lane & 31;
    const int rowA = node0 + r32;
    const int arow = (rowA < n) ? rowA : (n - 1);
    const int koff = (lane >> 5) * 8;

    f32x16 acc[4];
#pragma unroll
    for (int c = 0; c < 4; ++c) acc[c] = (f32x16)(0.0f);

#pragma unroll
    for (int half = 0; half < 2; ++half) {
        const short* A = (half ? hin : agg) + (size_t)arow * 128 + koff;
        const short* B0 = WF + half * 16384 + lane * 8;
#pragma unroll
        for (int kt = 0; kt < 8; ++kt) {
            f16x8 a = __builtin_bit_cast(f16x8, *(const short8*)(A + kt * 16));
            const short* Bp = B0 + kt * 2048;
#pragma unroll
            for (int ct = 0; ct < 4; ++ct) {
                f16x8 b = __builtin_bit_cast(f16x8, *(const short8*)(Bp + ct * 512));
                acc[ct] = __builtin_amdgcn_mfma_f32_32x32x16_f16(a, b, acc[ct], 0, 0, 0);
            }
        }
    }

    float sv[4], tv[4], wv[4];
#pragma unroll
    for (int ct = 0; ct < 4; ++ct) {
        int c = ct * 32 + r32;
        sv[ct] = gamma[c] * rsqrtf(var[c] + EPS);
        tv[ct] = beta[c] - mean[c] * sv[ct] + brel[c] * sv[ct];
        wv[ct] = POOL ? Wout[c] : 0.f;
    }

    if (!POOL) {
#pragma unroll
        for (int ct = 0; ct < 4; ++ct) {
            int c = ct * 32 + r32;
#pragma unroll
            for (int r = 0; r < 16; ++r) {
                int row = (r & 3) + 8 * (r >> 2) + 4 * (lane >> 5);
                int node = node0 + row;
                if (node < n) {
                    float v = acc[ct][r] * sv[ct] + tv[ct];
                    if (RELU) v = fmaxf(v, 0.f);
                    hout[(size_t)node * 128 + c] = f2h(v);
                    if (WRITE8) {
                        uint p = __builtin_amdgcn_cvt_pk_fp8_f32(v, v, 0, 0);
                        h8out[(size_t)node * 128 + c] = (uchar)p;
                    }
                }
            }
        }
    } else {
        // per-node dot with Wout (BN folded); each 32-lane half owns full rows
#pragma unroll
        for (int r = 0; r < 16; ++r) {
            float p = 0.f;
#pragma unroll
            for (int ct = 0; ct < 4; ++ct) p += (acc[ct][r] * sv[ct] + tv[ct]) * wv[ct];
#pragma unroll
            for (int d = 1; d < 32; d <<= 1) p += __shfl_xor(p, d);
            int row = (r & 3) + 8 * (r >> 2) + 4 * (lane >> 5);
            if (r32 == 0 && node0 + row < n) pnode[(tid >> 6) * 32 + row] = p;
        }
        __syncthreads();
        const int T0 = blockIdx.x * 128;
        if (tid < 128 && T0 + tid < n) {
            int gg = batch[T0 + tid];
            atomicAdd(&pg[gg], pnode[tid]);
            atomicAdd(&pc[gg], 1);
        }
        __syncthreads();
        if (tid < 64 && pc[tid] > 0) {
            atomicAdd(&gscal[tid], pg[tid]);
            atomicAdd(&gcnt[tid], pc[tid]);
        }
    }
}

__global__ void out_kernel(const float* __restrict__ gscal, const int* __restrict__ gcnt,
                           const float* __restrict__ bout, float* __restrict__ out, int G) {
    int g = threadIdx.x;
    if (g < G) out[g] = gscal[g] / fmaxf((float)gcnt[g], 1.0f) + bout[0];
}

// ---------------------------------------------------------------- launch
extern "C" void kernel_launch(void* const* d_in, const int* in_sizes, int n_in,
                              void* d_out, int out_size, void* d_ws, size_t ws_size,
                              hipStream_t stream) {
    const int N = in_sizes[0];            // 100000 (< 2^17, required by stage packing)
    const int E = in_sizes[1] / 2;
    const int G = 64;

    const float* x     = (const float*)d_in[0];
    const int*   ei    = (const int*)d_in[1];
    const int*   batch = (const int*)d_in[2];
    const int*   src   = ei;
    const int*   dst   = ei + E;

    const float* Wrel1 = (const float*)d_in[3];
    const float* brel1 = (const float*)d_in[4];
    const float* Wroot1= (const float*)d_in[5];
    const float* g1    = (const float*)d_in[6];
    const float* be1   = (const float*)d_in[7];
    const float* m1    = (const float*)d_in[8];
    const float* v1    = (const float*)d_in[9];
    const float* Wrel2 = (const float*)d_in[10];
    const float* brel2 = (const float*)d_in[11];
    const float* Wroot2= (const float*)d_in[12];
    const float* g2    = (const float*)d_in[13];
    const float* be2   = (const float*)d_in[14];
    const float* m2    = (const float*)d_in[15];
    const float* v2    = (const float*)d_in[16];
    const float* Wrel3 = (const float*)d_in[17];
    const float* brel3 = (const float*)d_in[18];
    const float* Wroot3= (const float*)d_in[19];
    const float* g3    = (const float*)d_in[20];
    const float* be3   = (const float*)d_in[21];
    const float* m3    = (const float*)d_in[22];
    const float* v3    = (const float*)d_in[23];
    const float* Wout  = (const float*)d_in[24];
    const float* bout  = (const float*)d_in[25];

    float* out = (float*)d_out;

    const int NB   = (N >> BSH) + 1;                 // 391 buckets of 256 dsts
    const int NBLK = (E + SCAT_E - 1) / SCAT_E;      // 391 scatter blocks

    // workspace carve (512B aligned)
    char* w = (char*)d_ws;
    auto alloc = [&](size_t bytes) { char* p = w; w += (bytes + 511) & ~(size_t)511; return p; };
    int*    rowptr = (int*)alloc((size_t)(N + 1) * 4);
    int*    bcnt   = (int*)alloc(NBMAX * 4);
    int*    gcur   = (int*)alloc((NBMAX + 1) * 4);
    int*    cnt2d  = (int*)alloc((size_t)NBLK * NB * 4);
    uint*   stage  = (uint*)alloc((size_t)E * 4);
    int*    eidx   = (int*)alloc((size_t)E * 4);
    ushort* hA     = (ushort*)alloc((size_t)N * 128 * 2);   // f16 [N][128]
    ushort* hB     = (ushort*)alloc((size_t)N * 128 * 2);   // f16 [N][128]
    ushort* aggb   = (ushort*)alloc((size_t)N * 128 * 2);   // f16 [N][128]
    uchar*  h8     = (uchar*)alloc((size_t)N * 128);        // fp8 shadow [N][128]
    ushort* WF2    = (ushort*)alloc(32768 * 2);
    ushort* WF3    = (ushort*)alloc(32768 * 2);
    float*  gscal  = (float*)alloc((size_t)G * 4);
    int*    gcnt   = (int*)alloc((size_t)G * 4);

    hipMemsetAsync(gscal, 0, (size_t)G * 4, stream);
    hipMemsetAsync(gcnt, 0, (size_t)G * 4, stream);

    // CSR build: 2D hist -> per-bucket scan over blocks -> bucket-base scan ->
    // deterministic sorted scatter -> per-bucket finalize. Zero global atomics.
    hist2d_kernel<<<NBLK, 256, 0, stream>>>(dst, cnt2d, E, NB);
    scan2d_kernel<<<(NB + 3) / 4, 256, 0, stream>>>(cnt2d, bcnt, NB, NBLK);
    scan_gcur_kernel<<<1, 256, 0, stream>>>(bcnt, gcur, NB);
    bucket_scatter_kernel<<<NBLK, 256, 0, stream>>>(src, dst, gcur, cnt2d, stage, E, NB);
    bucket_final_kernel<<<NB, 256, 0, stream>>>(stage, gcur, rowptr, eidx, N);

    // weight fragments
    wf_prep_kernel<<<256, 256, 0, stream>>>(Wrel2, Wroot2, Wrel3, Wroot3, WF2, WF3);

    // layer 1 (Cin=1): gather + BN + relu fused, writes f16 + fp8 shadow
    layer1_fused_kernel<<<(N + 15) / 16, 256, 0, stream>>>(x, rowptr, eidx, Wrel1, brel1,
                                                           Wroot1, g1, be1, m1, v1, hA, h8, N);

    const int nwt     = (N + 31) / 32;
    const int convBlk = (nwt + 3) / 4;
    const int gBlk    = (N + 3) / 4;

    // layer 2: gather (fp8) -> fused conv (writes hB f16 + fp8 shadow)
    gather_fp8_kernel<<<gBlk, 256, 0, stream>>>(h8, rowptr, eidx, aggb, N);
    conv_mfma_kernel<1, 1, 0><<<convBlk, 256, 0, stream>>>(
        (const short*)aggb, (const short*)hA, (const short*)WF2, brel2, g2, be2, m2, v2,
        hB, h8, nullptr, nullptr, nullptr, nullptr, N);

    // layer 3: gather -> fused conv + mean-pool dot(W_out) epilogue (no h output)
    gather_fp8_kernel<<<gBlk, 256, 0, stream>>>(h8, rowptr, eidx, aggb, N);
    conv_mfma_kernel<0, 0, 1><<<convBlk, 256, 0, stream>>>(
        (const short*)aggb, (const short*)hB, (const short*)WF3, brel3, g3, be3, m3, v3,
        nullptr, nullptr, batch, Wout, gscal, gcnt, N);

    // output
    out_kernel<<<1, 64, 0, stream>>>(gscal, gcnt, bout, out, G);
}

// Round 14
// 275.512 us; speedup vs baseline: 1.1168x; 1.1168x over previous
//
#include <hip/hip_runtime.h>

typedef unsigned int uint;
typedef unsigned short ushort;
typedef unsigned char uchar;

#define EPS 1e-5f
#define BSH 8        // bucket = 256 dst nodes
#define NBMAX 512
#define BCAP 10240   // LDS-cached bucket capacity (edges) in bucket_final
#define SCAT_E 8192  // edges per scatter/hist block

typedef __attribute__((ext_vector_type(8))) short short8;
typedef __attribute__((ext_vector_type(16))) float f32x16;
typedef __attribute__((ext_vector_type(2))) float float2v;
typedef __attribute__((ext_vector_type(2))) _Float16 half2v;
typedef __attribute__((ext_vector_type(8))) _Float16 f16x8;

static __device__ __forceinline__ ushort f2h(float f) {
    return __builtin_bit_cast(ushort, (_Float16)f);
}
static __device__ __forceinline__ half2v u2h(uint u) {
    return __builtin_bit_cast(half2v, u);
}

// ---------------------------------------------------------------- CSR build (atomic-free allocation)
// S1: per-block LDS histogram -> cnt2d[blk][NB] (coalesced row write, no atomics)
__global__ __launch_bounds__(256) void hist2d_kernel(const int* __restrict__ dst,
                                                     int* __restrict__ cnt2d, int E, int NB) {
    __shared__ int lh[NBMAX];
    const int tid = threadIdx.x;
    for (int t = tid; t < NB; t += 256) lh[t] = 0;
    __syncthreads();
    const int base = blockIdx.x * SCAT_E, end = min(base + SCAT_E, E);
    for (int i = base + tid; i < end; i += 256) atomicAdd(&lh[dst[i] >> BSH], 1);
    __syncthreads();
    int* row = cnt2d + (size_t)blockIdx.x * NB;
    for (int t = tid; t < NB; t += 256) row[t] = lh[t];
}

// S2: per-bucket exclusive scan of cnt2d over the block dimension (one wave per bucket)
__global__ __launch_bounds__(256) void scan2d_kernel(int* __restrict__ cnt2d,
                                                     int* __restrict__ bcnt, int NB, int NBLK) {
    const int b = blockIdx.x * 4 + (threadIdx.x >> 6);
    if (b >= NB) return;
    const int lane = threadIdx.x & 63;
    int carry = 0;
    for (int c0 = 0; c0 < NBLK; c0 += 64) {
        int idx = c0 + lane;
        int v = (idx < NBLK) ? cnt2d[(size_t)idx * NB + b] : 0;
        int inc = v;
#pragma unroll
        for (int d = 1; d < 64; d <<= 1) { int u = __shfl_up(inc, d); if (lane >= d) inc += u; }
        if (idx < NBLK) cnt2d[(size_t)idx * NB + b] = inc - v + carry;
        carry += __shfl(inc, 63);
    }
    if (lane == 0) bcnt[b] = carry;
}

// S3: exclusive scan bcnt -> gcur (single block); also writes gcur[nb] = total
__global__ void scan_gcur_kernel(const int* __restrict__ bcnt, int* __restrict__ gcur, int nb) {
    __shared__ int wsum[4];
    const int t = threadIdx.x;
    int e[4], s = 0;
#pragma unroll
    for (int k = 0; k < 4; ++k) {
        int idx = t * 4 + k;
        e[k] = (idx < nb) ? bcnt[idx] : 0;
        s += e[k];
    }
    int lane = t & 63, w = t >> 6;
    int v = s;
#pragma unroll
    for (int d = 1; d < 64; d <<= 1) { int u = __shfl_up(v, d); if (lane >= d) v += u; }
    if (lane == 63) wsum[w] = v;
    __syncthreads();
    int off = 0;
    for (int k = 0; k < w; ++k) off += wsum[k];
    int run = off + v - s;
#pragma unroll
    for (int k = 0; k < 4; ++k) {
        int idx = t * 4 + k;
        if (idx < nb) gcur[idx] = run;
        run += e[k];
    }
    if (t == 0) gcur[nb] = wsum[0] + wsum[1] + wsum[2] + wsum[3];
}

// S4: LDS counting sort per block, run-contiguous stage writes; run base is
// gcur[b] + cnt2d[blk][b] -- fully deterministic, zero global atomics.
// packed 4B: src | (dst & 255) << 17
__global__ __launch_bounds__(256) void bucket_scatter_kernel(const int* __restrict__ src,
                                                             const int* __restrict__ dst,
                                                             const int* __restrict__ gcur,
                                                             const int* __restrict__ cnt2d,
                                                             uint* __restrict__ stage,
                                                             int E, int NB) {
    __shared__ uint sedge[SCAT_E];
    __shared__ ushort sbkt[SCAT_E];
    __shared__ int lh[NBMAX];
    __shared__ int lofs[NBMAX + 1];
    __shared__ int lbase[NBMAX];
    __shared__ int wsum[4];
    const int tid = threadIdx.x;
    const int base = blockIdx.x * SCAT_E;
    const int len = min(base + SCAT_E, E) - base;
    const int* myrow = cnt2d + (size_t)blockIdx.x * NB;

    for (int t = tid; t < NB; t += 256) lh[t] = 0;
    __syncthreads();
    // pass 1: histogram
    for (int i = tid; i < len; i += 256) atomicAdd(&lh[dst[base + i] >> BSH], 1);
    __syncthreads();
    // local exclusive scan (2 elems/thread, NB<=512) + deterministic global bases
    const int i0 = tid * 2, i1 = tid * 2 + 1;
    int e0 = (i0 < NB) ? lh[i0] : 0;
    int e1 = (i1 < NB) ? lh[i1] : 0;
    int s = e0 + e1;
    int lane = tid & 63, w = tid >> 6;
    int v = s;
#pragma unroll
    for (int d = 1; d < 64; d <<= 1) { int u = __shfl_up(v, d); if (lane >= d) v += u; }
    if (lane == 63) wsum[w] = v;
    __syncthreads();
    int off = 0;
    for (int k = 0; k < w; ++k) off += wsum[k];
    int run = off + v - s;
    if (i0 <= NB) lofs[i0] = run;
    if (i0 < NB) lbase[i0] = gcur[i0] + myrow[i0];
    run += e0;
    if (i1 <= NB) lofs[i1] = run;
    if (i1 < NB) lbase[i1] = gcur[i1] + myrow[i1];
    __syncthreads();
    // reset cursors
    for (int t = tid; t < NB; t += 256) lh[t] = 0;
    __syncthreads();
    // pass 2: LDS scatter into sorted order, recording bucket per position
    for (int i = tid; i < len; i += 256) {
        int d = dst[base + i];
        int b = d >> BSH;
        int r = atomicAdd(&lh[b], 1);
        int pos = lofs[b] + r;
        sedge[pos] = (uint)src[base + i] | ((uint)(d & 255) << 17);
        sbkt[pos] = (ushort)b;
    }
    __syncthreads();
    // pass 3: linear copy; consecutive i -> consecutive stage slots within runs
    for (int i = tid; i < len; i += 256) {
        int b = sbkt[i];
        stage[lbase[b] + (i - lofs[b])] = sedge[i];
    }
}

// B: per-bucket finalize: LDS hist -> scan -> rowptr + place via LDS cursors
__global__ __launch_bounds__(256) void bucket_final_kernel(const uint* __restrict__ stage,
                                                           const int* __restrict__ gcur,
                                                           int* __restrict__ rowptr,
                                                           int* __restrict__ eidx, int n) {
    __shared__ uint sbuf[BCAP];
    __shared__ int cnt[256];
    __shared__ int wsum[4];
    const int b = blockIdx.x, tid = threadIdx.x;
    const int r0 = gcur[b];
    const int r1 = gcur[b + 1];
    const int len = r1 - r0;
    const bool inl = (len <= BCAP);
    cnt[tid] = 0;
    if (inl) for (int i = tid; i < len; i += 256) sbuf[i] = stage[r0 + i];
    __syncthreads();
    for (int i = tid; i < len; i += 256) {
        uint v = inl ? sbuf[i] : stage[r0 + i];
        atomicAdd(&cnt[v >> 17], 1);
    }
    __syncthreads();
    int orig = cnt[tid], v = orig;
    int lane = tid & 63, w = tid >> 6;
#pragma unroll
    for (int d2 = 1; d2 < 64; d2 <<= 1) { int u = __shfl_up(v, d2); if (lane >= d2) v += u; }
    if (lane == 63) wsum[w] = v;
    __syncthreads();
    int off = 0;
    for (int k = 0; k < w; ++k) off += wsum[k];
    const int excl = r0 + off + v - orig;   // absolute exclusive slot base
    const int d = (b << BSH) + tid;
    if (d <= n) rowptr[d] = excl;           // last bucket covers rowptr[n] = E
    __syncthreads();
    cnt[tid] = excl;
    __syncthreads();
    for (int i = tid; i < len; i += 256) {
        uint pv = inl ? sbuf[i] : stage[r0 + i];
        int slot = atomicAdd(&cnt[pv >> 17], 1);
        eidx[slot] = (int)(pv & 0x1FFFFu);
    }
}

// ---------------------------------------------------------------- layer 1 fused (Cin = 1)
// 16-lane group per node; writes f16 h1 row AND fp8 shadow row
__global__ __launch_bounds__(256) void layer1_fused_kernel(
    const float* __restrict__ x, const int* __restrict__ rowptr, const int* __restrict__ eidx,
    const float* __restrict__ Wrel, const float* __restrict__ brel,
    const float* __restrict__ Wroot, const float* __restrict__ gamma,
    const float* __restrict__ beta, const float* __restrict__ mean,
    const float* __restrict__ var, ushort* __restrict__ h1, uchar* __restrict__ h8, int n) {
    __shared__ float A[128], B[128], C[128];
    const int tid = threadIdx.x;
    if (tid < 128) {
        float sc = gamma[tid] * rsqrtf(var[tid] + EPS);
        A[tid] = Wrel[tid] * sc;
        B[tid] = Wroot[tid] * sc;
        C[tid] = beta[tid] + (brel[tid] - mean[tid]) * sc;
    }
    __syncthreads();
    const int g16 = tid >> 4;
    const int l16 = tid & 15;
    const int node = blockIdx.x * 16 + g16;
    if (node >= n) return;
    const int e0 = rowptr[node], e1 = rowptr[node + 1];
    float acc = 0.f;
    for (int e = e0 + l16; e < e1; e += 16) acc += x[eidx[e]];
#pragma unroll
    for (int d = 1; d < 16; d <<= 1) acc += __shfl_xor(acc, d);
    const float xi = x[node];
    float vv[8];
    uint4 o;
    ushort* op = (ushort*)&o;
#pragma unroll
    for (int j = 0; j < 8; ++j) {
        int c = l16 * 8 + j;
        vv[j] = fmaxf(acc * A[c] + xi * B[c] + C[c], 0.f);
        op[j] = f2h(vv[j]);
    }
    *((uint4*)(h1 + (size_t)node * 128) + l16) = o;
    uint p0 = 0, p1 = 0;
    p0 = __builtin_amdgcn_cvt_pk_fp8_f32(vv[0], vv[1], 0, 0);
    p0 = __builtin_amdgcn_cvt_pk_fp8_f32(vv[2], vv[3], p0, 1);
    p1 = __builtin_amdgcn_cvt_pk_fp8_f32(vv[4], vv[5], 0, 0);
    p1 = __builtin_amdgcn_cvt_pk_fp8_f32(vv[6], vv[7], p1, 1);
    uint2 o8; o8.x = p0; o8.y = p1;
    ((uint2*)(h8 + (size_t)node * 128))[l16] = o8;
}

// ---------------------------------------------------------------- aggregation (fp8 source, H=128)
// one node per wave; 16 lanes per edge (uint2 = 8B of the 128B fp8 row); 4 edge slots;
// srcs broadcast via shfl (one VGPR holds 64 edge ids -> VGPR=32, occupancy-bound
// random gather at max resident waves); f32 accumulation via v_cvt_pk_f32_fp8.
__global__ __launch_bounds__(256) void gather_fp8_kernel(const uchar* __restrict__ h8,
                                                         const int* __restrict__ rowptr,
                                                         const int* __restrict__ eidx,
                                                         ushort* __restrict__ agg, int n) {
    const int node = blockIdx.x * 4 + (threadIdx.x >> 6);
    if (node >= n) return;
    const int lane = threadIdx.x & 63;
    const int g = lane >> 4;        // edge slot 0..3
    const int c8 = lane & 15;       // 8B slice of the 128B row
    const uint2* hq = (const uint2*)h8;   // 16 uint2 per row
    const int e0 = rowptr[node];
    const int len = rowptr[node + 1] - e0;

    float2v a0 = {0.f, 0.f}, a1 = {0.f, 0.f}, a2 = {0.f, 0.f}, a3 = {0.f, 0.f};

#define ACC8(u)                                                        \
    do {                                                               \
        a0 += __builtin_amdgcn_cvt_pk_f32_fp8((int)(u).x, 0);          \
        a1 += __builtin_amdgcn_cvt_pk_f32_fp8((int)(u).x, 1);          \
        a2 += __builtin_amdgcn_cvt_pk_f32_fp8((int)(u).y, 0);          \
        a3 += __builtin_amdgcn_cvt_pk_f32_fp8((int)(u).y, 1);          \
    } while (0)

    for (int base = 0; base < len; base += 64) {
        const int cnt = min(len - base, 64);
        int msrc = (lane < cnt) ? eidx[e0 + base + lane] : 0;
        const int kfull = cnt >> 2;     // complete groups of 4 edges
        int k = 0;
        for (; k + 8 <= kfull; k += 8) {    // 32 edges, 8 loads in flight per lane
            uint2 u[8];
#pragma unroll
            for (int s = 0; s < 8; ++s) {
                int src = __shfl(msrc, (k + s) * 4 + g);
                u[s] = hq[(size_t)src * 16 + c8];
            }
#pragma unroll
            for (int s = 0; s < 8; ++s) ACC8(u[s]);
        }
        for (; k < kfull; ++k) {
            int src = __shfl(msrc, k * 4 + g);
            uint2 u = hq[(size_t)src * 16 + c8];
            ACC8(u);
        }
        const int rem = cnt & 3;
        if (rem) {
            int idx = (kfull << 2) + g;     // <= 63 always
            int src = __shfl(msrc, idx);
            if (g < rem) {
                uint2 u = hq[(size_t)src * 16 + c8];
                ACC8(u);
            }
        }
    }
#undef ACC8

    // reduce across the 4 edge slots (lanes with equal c8)
#pragma unroll
    for (int d = 16; d <= 32; d <<= 1) {
        a0[0] += __shfl_xor(a0[0], d); a0[1] += __shfl_xor(a0[1], d);
        a1[0] += __shfl_xor(a1[0], d); a1[1] += __shfl_xor(a1[1], d);
        a2[0] += __shfl_xor(a2[0], d); a2[1] += __shfl_xor(a2[1], d);
        a3[0] += __shfl_xor(a3[0], d); a3[1] += __shfl_xor(a3[1], d);
    }
    if (g == 0) {
        uint4 o;
        ushort* op = (ushort*)&o;
        op[0] = f2h(a0[0]); op[1] = f2h(a0[1]);
        op[2] = f2h(a1[0]); op[3] = f2h(a1[1]);
        op[4] = f2h(a2[0]); op[5] = f2h(a2[1]);
        op[6] = f2h(a3[0]); op[7] = f2h(a3[1]);
        ((uint4*)agg)[(size_t)node * 16 + c8] = o;
    }
}

// ---------------------------------------------------------------- weight fragment prep
// WF layout: [half][kt 0..7][ct 0..3][lane 0..63][j 0..7]  (f16)
// frag element = W_half[ct*32 + (lane&31)][kt*16 + (lane>>5)*8 + j]
__global__ void wf_prep_kernel(const float* __restrict__ W0, const float* __restrict__ W1,
                               const float* __restrict__ W2, const float* __restrict__ W3,
                               ushort* __restrict__ WF2, ushort* __restrict__ WF3) {
    int i = blockIdx.x * 256 + threadIdx.x;   // 65536 threads
    const float* Ws[4] = {W0, W1, W2, W3};
    int mat = i >> 14;
    int m = i & 16383;
    int j = m & 7, lane = (m >> 3) & 63, ct = (m >> 9) & 3, kt = (m >> 11) & 7;
    int row = ct * 32 + (lane & 31);
    int col = kt * 16 + ((lane >> 5) * 8) + j;
    float v = Ws[mat][row * 128 + col];
    ushort* dstp = (mat < 2) ? WF2 : WF3;
    dstp[(mat & 1) * 16384 + m] = f2h(v);
}

// ---------------------------------------------------------------- fused conv via MFMA (f16)
// POOL=0: write f16 (+fp8 shadow if WRITE8). POOL=1: no h-output; fold BN+Wout,
// per-node dot -> LDS -> per-graph accumulation (mean-pool numerator + counts).
template <int RELU, int WRITE8, int POOL>
__global__ __launch_bounds__(256) void conv_mfma_kernel(
    const short* __restrict__ agg, const short* __restrict__ hin,
    const short* __restrict__ WF,
    const float* __restrict__ brel, const float* __restrict__ gamma,
    const float* __restrict__ beta, const float* __restrict__ mean,
    const float* __restrict__ var,
    ushort* __restrict__ hout, uchar* __restrict__ h8out,
    const int* __restrict__ batch, const float* __restrict__ Wout,
    float* __restrict__ gscal, int* __restrict__ gcnt, int n) {
    __shared__ float pnode[128];
    __shared__ float pg[64];
    __shared__ int pc[64];
    const int tid = threadIdx.x;
    if (POOL && tid < 64) { pg[tid] = 0.f; pc[tid] = 0; }
    const int lane = tid & 63;
    const int wt = blockIdx.x * 4 + (tid >> 6);
    const int node0 = wt * 32;
    if (!POOL && node0 >= n) return;
    const int r32 = lane & 31;
    const int rowA = node0 + r32;
    const int arow = (rowA < n) ? rowA : (n - 1);
    const int koff = (lane >> 5) * 8;

    f32x16 acc[4];
#pragma unroll
    for (int c = 0; c < 4; ++c) acc[c] = (f32x16)(0.0f);

#pragma unroll
    for (int half = 0; half < 2; ++half) {
        const short* A = (half ? hin : agg) + (size_t)arow * 128 + koff;
        const short* B0 = WF + half * 16384 + lane * 8;
#pragma unroll
        for (int kt = 0; kt < 8; ++kt) {
            f16x8 a = __builtin_bit_cast(f16x8, *(const short8*)(A + kt * 16));
            const short* Bp = B0 + kt * 2048;
#pragma unroll
            for (int ct = 0; ct < 4; ++ct) {
                f16x8 b = __builtin_bit_cast(f16x8, *(const short8*)(Bp + ct * 512));
                acc[ct] = __builtin_amdgcn_mfma_f32_32x32x16_f16(a, b, acc[ct], 0, 0, 0);
            }
        }
    }

    float sv[4], tv[4], wv[4];
#pragma unroll
    for (int ct = 0; ct < 4; ++ct) {
        int c = ct * 32 + r32;
        sv[ct] = gamma[c] * rsqrtf(var[c] + EPS);
        tv[ct] = beta[c] - mean[c] * sv[ct] + brel[c] * sv[ct];
        wv[ct] = POOL ? Wout[c] : 0.f;
    }

    if (!POOL) {
#pragma unroll
        for (int ct = 0; ct < 4; ++ct) {
            int c = ct * 32 + r32;
#pragma unroll
            for (int r = 0; r < 16; ++r) {
                int row = (r & 3) + 8 * (r >> 2) + 4 * (lane >> 5);
                int node = node0 + row;
                if (node < n) {
                    float v = acc[ct][r] * sv[ct] + tv[ct];
                    if (RELU) v = fmaxf(v, 0.f);
                    hout[(size_t)node * 128 + c] = f2h(v);
                    if (WRITE8) {
                        uint p = __builtin_amdgcn_cvt_pk_fp8_f32(v, v, 0, 0);
                        h8out[(size_t)node * 128 + c] = (uchar)p;
                    }
                }
            }
        }
    } else {
        // per-node dot with Wout (BN folded); each 32-lane half owns full rows
#pragma unroll
        for (int r = 0; r < 16; ++r) {
            float p = 0.f;
#pragma unroll
            for (int ct = 0; ct < 4; ++ct) p += (acc[ct][r] * sv[ct] + tv[ct]) * wv[ct];
#pragma unroll
            for (int d = 1; d < 32; d <<= 1) p += __shfl_xor(p, d);
            int row = (r & 3) + 8 * (r >> 2) + 4 * (lane >> 5);
            if (r32 == 0 && node0 + row < n) pnode[(tid >> 6) * 32 + row] = p;
        }
        __syncthreads();
        const int T0 = blockIdx.x * 128;
        if (tid < 128 && T0 + tid < n) {
            int gg = batch[T0 + tid];
            atomicAdd(&pg[gg], pnode[tid]);
            atomicAdd(&pc[gg], 1);
        }
        __syncthreads();
        if (tid < 64 && pc[tid] > 0) {
            atomicAdd(&gscal[tid], pg[tid]);
            atomicAdd(&gcnt[tid], pc[tid]);
        }
    }
}

__global__ void out_kernel(const float* __restrict__ gscal, const int* __restrict__ gcnt,
                           const float* __restrict__ bout, float* __restrict__ out, int G) {
    int g = threadIdx.x;
    if (g < G) out[g] = gscal[g] / fmaxf((float)gcnt[g], 1.0f) + bout[0];
}

// ---------------------------------------------------------------- launch
extern "C" void kernel_launch(void* const* d_in, const int* in_sizes, int n_in,
                              void* d_out, int out_size, void* d_ws, size_t ws_size,
                              hipStream_t stream) {
    const int N = in_sizes[0];            // 100000 (< 2^17, required by stage packing)
    const int E = in_sizes[1] / 2;
    const int G = 64;

    const float* x     = (const float*)d_in[0];
    const int*   ei    = (const int*)d_in[1];
    const int*   batch = (const int*)d_in[2];
    const int*   src   = ei;
    const int*   dst   = ei + E;

    const float* Wrel1 = (const float*)d_in[3];
    const float* brel1 = (const float*)d_in[4];
    const float* Wroot1= (const float*)d_in[5];
    const float* g1    = (const float*)d_in[6];
    const float* be1   = (const float*)d_in[7];
    const float* m1    = (const float*)d_in[8];
    const float* v1    = (const float*)d_in[9];
    const float* Wrel2 = (const float*)d_in[10];
    const float* brel2 = (const float*)d_in[11];
    const float* Wroot2= (const float*)d_in[12];
    const float* g2    = (const float*)d_in[13];
    const float* be2   = (const float*)d_in[14];
    const float* m2    = (const float*)d_in[15];
    const float* v2    = (const float*)d_in[16];
    const float* Wrel3 = (const float*)d_in[17];
    const float* brel3 = (const float*)d_in[18];
    const float* Wroot3= (const float*)d_in[19];
    const float* g3    = (const float*)d_in[20];
    const float* be3   = (const float*)d_in[21];
    const float* m3    = (const float*)d_in[22];
    const float* v3    = (const float*)d_in[23];
    const float* Wout  = (const float*)d_in[24];
    const float* bout  = (const float*)d_in[25];

    float* out = (float*)d_out;

    const int NB   = (N >> BSH) + 1;                 // 391 buckets of 256 dsts
    const int NBLK = (E + SCAT_E - 1) / SCAT_E;      // 391 scatter blocks

    // workspace carve (512B aligned)
    char* w = (char*)d_ws;
    auto alloc = [&](size_t bytes) { char* p = w; w += (bytes + 511) & ~(size_t)511; return p; };
    int*    rowptr = (int*)alloc((size_t)(N + 1) * 4);
    int*    bcnt   = (int*)alloc(NBMAX * 4);
    int*    gcur   = (int*)alloc((NBMAX + 1) * 4);
    int*    cnt2d  = (int*)alloc((size_t)NBLK * NB * 4);
    uint*   stage  = (uint*)alloc((size_t)E * 4);
    int*    eidx   = (int*)alloc((size_t)E * 4);
    ushort* hA     = (ushort*)alloc((size_t)N * 128 * 2);   // f16 [N][128]
    ushort* hB     = (ushort*)alloc((size_t)N * 128 * 2);   // f16 [N][128]
    ushort* aggb   = (ushort*)alloc((size_t)N * 128 * 2);   // f16 [N][128]
    uchar*  h8     = (uchar*)alloc((size_t)N * 128);        // fp8 shadow [N][128]
    ushort* WF2    = (ushort*)alloc(32768 * 2);
    ushort* WF3    = (ushort*)alloc(32768 * 2);
    float*  gscal  = (float*)alloc((size_t)G * 4);
    int*    gcnt   = (int*)alloc((size_t)G * 4);

    hipMemsetAsync(gscal, 0, (size_t)G * 4, stream);
    hipMemsetAsync(gcnt, 0, (size_t)G * 4, stream);

    // CSR build: 2D hist -> per-bucket scan over blocks -> bucket-base scan ->
    // deterministic sorted scatter -> per-bucket finalize. Zero global atomics.
    hist2d_kernel<<<NBLK, 256, 0, stream>>>(dst, cnt2d, E, NB);
    scan2d_kernel<<<(NB + 3) / 4, 256, 0, stream>>>(cnt2d, bcnt, NB, NBLK);
    scan_gcur_kernel<<<1, 256, 0, stream>>>(bcnt, gcur, NB);
    bucket_scatter_kernel<<<NBLK, 256, 0, stream>>>(src, dst, gcur, cnt2d, stage, E, NB);
    bucket_final_kernel<<<NB, 256, 0, stream>>>(stage, gcur, rowptr, eidx, N);

    // weight fragments
    wf_prep_kernel<<<256, 256, 0, stream>>>(Wrel2, Wroot2, Wrel3, Wroot3, WF2, WF3);

    // layer 1 (Cin=1): gather + BN + relu fused, writes f16 + fp8 shadow
    layer1_fused_kernel<<<(N + 15) / 16, 256, 0, stream>>>(x, rowptr, eidx, Wrel1, brel1,
                                                           Wroot1, g1, be1, m1, v1, hA, h8, N);

    const int nwt     = (N + 31) / 32;
    const int convBlk = (nwt + 3) / 4;
    const int gBlk    = (N + 3) / 4;

    // layer 2: gather (fp8) -> fused conv (writes hB f16 + fp8 shadow)
    gather_fp8_kernel<<<gBlk, 256, 0, stream>>>(h8, rowptr, eidx, aggb, N);
    conv_mfma_kernel<1, 1, 0><<<convBlk, 256, 0, stream>>>(
        (const short*)aggb, (const short*)hA, (const short*)WF2, brel2, g2, be2, m2, v2,
        hB, h8, nullptr, nullptr, nullptr, nullptr, N);

    // layer 3: gather -> fused conv + mean-pool dot(W_out) epilogue (no h output)
    gather_fp8_kernel<<<gBlk, 256, 0, stream>>>(h8, rowptr, eidx, aggb, N);
    conv_mfma_kernel<0, 0, 1><<<convBlk, 256, 0, stream>>>(
        (const short*)aggb, (const short*)hB, (const short*)WF3, brel3, g3, be3, m3, v3,
        nullptr, nullptr, batch, Wout, gscal, gcnt, N);

    // output
    out_kernel<<<1, 64, 0, stream>>>(gscal, gcnt, bout, out, G);
}